// Round 8
// baseline (266.314 us; speedup 1.0000x reference)
//
#include <hip/hip_runtime.h>
#include <cmath>

#define HH 256
#define WW 256
#define BB 64
#define RR 4                 // tap radius: exp(-12.5)=3.7e-6 dropped -> error ~4e-5 << 0.1 thresh
#define OROWS 16             // output rows per block strip
#define NUNITS (BB * 16)     // 1024 blocks; residency ~8 blocks/CU at VGPR<=85 -> all resident

static __device__ __forceinline__ float bin(float v) { return (v > 0.0f) ? 1.0f : 0.0f; }
// bf16 truncation pack: rel err <= 0.4% << 0.101 threshold (proven r3/r6/r7)
static __device__ __forceinline__ unsigned pk2(float a, float b) {
    return (__float_as_uint(a) >> 16) | (__float_as_uint(b) & 0xffff0000u);
}
static __device__ __forceinline__ float up_lo(unsigned u) { return __uint_as_float(u << 16); }
static __device__ __forceinline__ float up_hi(unsigned u) { return __uint_as_float(u & 0xffff0000u); }

// ---------------------------------------------------------------------------
// One block per (b, 16-row strip), 192 threads = 3 waves, wave w == map w.
// Register-only splat (r7 structure). r7 post-mortem: the per-batch rendezvous
// was an atomic STORM — 64 counters packed in 2 cache lines, ~1024 pollers
// serializing at the coherence point (~150us; r2's grid.sync showed the same).
// This round:
//  - ws layout = one 128B line per batch: rec[b] = {cnt, max0, max1, max2}
//    -> 16 spinners/line instead of ~512.
//  - backoff: 256 polls at s_sleep(2), then s_sleep(8). Bounded (no-hang).
//  - maxes: 3 atomic loads per BLOCK -> LDS broadcast (was 3 per THREAD).
//  - acc bf16-packed into pk[32] BEFORE the spin: 32 regs live across barrier
//    -> no spill (r7's extra 55MB WRITE was a one-shot acc spill round-trip).
// map 0: x[:,2] s=1.0 -> ch1 ; map 1: x[:,1] -> ch2 ; map 2: x[:,3] s=0.5 -> ch3
// ---------------------------------------------------------------------------
__global__ __launch_bounds__(192, 3) void fused_kernel(const float* __restrict__ x,
                                                       float* __restrict__ out,
                                                       int* __restrict__ ws) {
    __shared__ unsigned mbuf[2][OROWS * 128];   // unnormalized t,c rows, bf16x2: 16 KB
    __shared__ float sinv[3];                   // 1/max per map

    // XCD-chunked swizzle: each batch's 16 blocks land on one XCD (L2 + fast spin).
    const int bid = blockIdx.x;
    const int unit = (bid & 7) * (NUNITS >> 3) + (bid >> 3);
    const int b = unit >> 4;
    const int strip = unit & 15;
    const int ti0 = strip * OROWS;
    const int tid = threadIdx.x;
    const int w = tid >> 6;          // wave == map index
    const int l = tid & 63;          // lane: pixels 4l..4l+3

    int* rec = ws + b * 32;          // private 128B line: [cnt, max0, max1, max2, pad..]

    const int src_c = (w == 0) ? 2 : ((w == 1) ? 1 : 3);
    // Hardcoded taps exp(-d^2/(2 s^2)): s=1.0 (maps 0,1), s=0.5 (map 2).
    const bool hsig = (w == 2);
    const float wm[RR + 1] = {
        1.0f,
        hsig ? 1.3533528e-1f  : 6.0653066e-1f,
        hsig ? 3.3546263e-4f  : 1.3533528e-1f,
        hsig ? 1.5229980e-8f  : 1.1108997e-2f,
        hsig ? 1.2664166e-14f : 3.3546263e-4f
    };

    // ---- ch0 copy: rows interleaved stride-3 across the 3 waves ----
    {
        const float* x0 = x + (((size_t)b * 4) << 16);
        float* o0 = out + (((size_t)b * 5) << 16);
#pragma unroll
        for (int k = 0; k < 6; ++k) {
            int r = 3 * k + w;
            if (r < OROWS) {
                size_t off = ((size_t)(ti0 + r) << 8) + 4 * l;
                *(float4*)&o0[off] = *(const float4*)&x0[off];
            }
        }
    }

    // ---- splat: 24 rows, register-only pipeline (no barriers) ----
    const float* xc = x + (((size_t)b * 4 + src_c) << 16);
    float4 acc[OROWS];
#pragma unroll
    for (int o = 0; o < OROWS; ++o) acc[o] = make_float4(0.f, 0.f, 0.f, 0.f);

#pragma unroll
    for (int r = 0; r < OROWS + 2 * RR; ++r) {
        const int gi = ti0 + r - RR;           // image row (uniform branch)
        if (gi >= 0 && gi < HH) {
            float4 q = *(const float4*)(xc + ((size_t)gi << 8) + 4 * l);
            float a0 = bin(q.x), a1 = bin(q.y), a2 = bin(q.z), a3 = bin(q.w);
            float v3 = __shfl_up(a3, 1, 64);   // px 4l-1
            float v2 = __shfl_up(a2, 1, 64);
            float v1 = __shfl_up(a1, 1, 64);
            float v0 = __shfl_up(a0, 1, 64);   // px 4l-4
            float v8 = __shfl_down(a0, 1, 64); // px 4l+4
            float v9 = __shfl_down(a1, 1, 64);
            float v10 = __shfl_down(a2, 1, 64);
            float v11 = __shfl_down(a3, 1, 64);
            if (l == 0)  { v0 = v1 = v2 = v3 = 0.f; }
            if (l == 63) { v8 = v9 = v10 = v11 = 0.f; }
            const float v4 = a0, v5 = a1, v6 = a2, v7 = a3;
            float h0 = wm[4]*(v0+v8)  + wm[3]*(v1+v7)  + wm[2]*(v2+v6) + wm[1]*(v3+v5) + wm[0]*v4;
            float h1 = wm[4]*(v1+v9)  + wm[3]*(v2+v8)  + wm[2]*(v3+v7) + wm[1]*(v4+v6) + wm[0]*v5;
            float h2 = wm[4]*(v2+v10) + wm[3]*(v3+v9)  + wm[2]*(v4+v8) + wm[1]*(v5+v7) + wm[0]*v6;
            float h3 = wm[4]*(v3+v11) + wm[3]*(v4+v10) + wm[2]*(v5+v9) + wm[1]*(v6+v8) + wm[0]*v7;
#pragma unroll
            for (int o = 0; o < OROWS; ++o) {
                if (o >= r - 2 * RR && o <= r) {       // compile-time (r,o consts)
                    int d = r - RR - o; if (d < 0) d = -d;
                    const float wk = wm[d];
                    acc[o].x += wk * h0; acc[o].y += wk * h1;
                    acc[o].z += wk * h2; acc[o].w += wk * h3;
                }
            }
        }
    }

    // ---- wave max -> atomicMax into batch-private line ----
    float lmax = 0.f;
#pragma unroll
    for (int o = 0; o < OROWS; ++o)
        lmax = fmaxf(lmax, fmaxf(fmaxf(acc[o].x, acc[o].y), fmaxf(acc[o].z, acc[o].w)));
#pragma unroll
    for (int off = 32; off > 0; off >>= 1)
        lmax = fmaxf(lmax, __shfl_down(lmax, off, 64));
    if (l == 0) atomicMax(&rec[1 + w], __float_as_int(lmax));

    // ---- pack acc -> bf16 pk[32]: only 32 regs live across the barrier ----
    unsigned pk[2 * OROWS];
#pragma unroll
    for (int o = 0; o < OROWS; ++o) {
        pk[2 * o]     = pk2(acc[o].x, acc[o].y);
        pk[2 * o + 1] = pk2(acc[o].z, acc[o].w);
    }
    // stash unnormalized t,c to LDS for ch4 (read after post-spin barrier)
    if (w < 2) {
#pragma unroll
        for (int o = 0; o < OROWS; ++o) {
            mbuf[w][o * 128 + 2 * l]     = pk[2 * o];
            mbuf[w][o * 128 + 2 * l + 1] = pk[2 * o + 1];
        }
    }

    // ---- per-batch rendezvous: 16 co-resident blocks, private cache line ----
    __syncthreads();                  // all 3 waves' atomicMax + mbuf writes done
    if (tid == 0) {
        __hip_atomic_fetch_add(&rec[0], 1, __ATOMIC_ACQ_REL, __HIP_MEMORY_SCOPE_AGENT);
        int it = 0;
        while (__hip_atomic_load(&rec[0], __ATOMIC_ACQUIRE, __HIP_MEMORY_SCOPE_AGENT) < 16
               && it < (1 << 20)) {
            if (it < 256) {
                __builtin_amdgcn_s_sleep(2);
            } else {
                __builtin_amdgcn_s_sleep(8);
            }
            ++it;
        }
    }
    __syncthreads();
    if (tid < 3) {                    // 3 atomic loads per BLOCK, then LDS broadcast
        float mxf = __int_as_float(__hip_atomic_load(&rec[1 + tid], __ATOMIC_ACQUIRE,
                                                     __HIP_MEMORY_SCOPE_AGENT));
        sinv[tid] = (mxf == 0.f) ? 1.f : (1.f / mxf);
    }
    __syncthreads();
    const float rm = sinv[w];
    const float r4 = sinv[0] * sinv[1];   // ch4 scale (t and c both unnormalized bf16)

    // ---- write own channel, normalized from pk ----
    float* oc = out + (((size_t)b * 5 + (w + 1)) << 16);
#pragma unroll
    for (int o = 0; o < OROWS; ++o) {
        unsigned p01 = pk[2 * o], p23 = pk[2 * o + 1];
        float4 t = make_float4(up_lo(p01) * rm, up_hi(p01) * rm,
                               up_lo(p23) * rm, up_hi(p23) * rm);
        *(float4*)&oc[((size_t)(ti0 + o) << 8) + 4 * l] = t;
    }

    // ---- ch4 = t*c*rt*rc from staged bf16, rows split stride-3 across waves ----
    float* o4 = out + (((size_t)b * 5 + 4) << 16);
#pragma unroll
    for (int k = 0; k < 6; ++k) {
        int r = 3 * k + w;
        if (r < OROWS) {
            unsigned t01 = mbuf[0][r * 128 + 2 * l], t23 = mbuf[0][r * 128 + 2 * l + 1];
            unsigned c01 = mbuf[1][r * 128 + 2 * l], c23 = mbuf[1][r * 128 + 2 * l + 1];
            float4 mul = make_float4(up_lo(t01) * up_lo(c01) * r4,
                                     up_hi(t01) * up_hi(c01) * r4,
                                     up_lo(t23) * up_lo(c23) * r4,
                                     up_hi(t23) * up_hi(c23) * r4);
            *(float4*)&o4[((size_t)(ti0 + r) << 8) + 4 * l] = mul;
        }
    }
}

extern "C" void kernel_launch(void* const* d_in, const int* in_sizes, int n_in,
                              void* d_out, int out_size, void* d_ws, size_t ws_size,
                              hipStream_t stream) {
    const float* x = (const float*)d_in[0];
    float* out = (float*)d_out;
    int* ws = (int*)d_ws;   // 64 batches x one 128B line = 8 KB

    (void)hipMemsetAsync(d_ws, 0, BB * 32 * sizeof(int), stream);  // capture-legal reset
    hipLaunchKernelGGL(fused_kernel, dim3(NUNITS), dim3(192), 0, stream, x, out, ws);
}

// Round 9
// 142.406 us; speedup vs baseline: 1.8701x; 1.8701x over previous
//
#include <hip/hip_runtime.h>
#include <cmath>

#define HH 256
#define WW 256
#define BB 64
#define RR 4               // tap radius: exp(-12.5)=3.7e-6 dropped -> error ~4e-5 << 0.1 thresh
#define OROWS 16           // output rows per block
#define TROWS (OROWS + 2*RR)  // 24 h-blurred rows in LDS
#define TSTR 260           // tmp row stride (dwords): 256 + 4 -> rows rotate 4 banks

#define MAPS_U32 ((size_t)192 * 32768)            // bf16 maps: 192 z-planes x 128KB
#define NEED_WS  (MAPS_U32 * 4 + 192 * 16 * 4)    // + strip maxes ~= 25.2 MB

static __device__ __forceinline__ float bin(float v) { return (v > 0.0f) ? 1.0f : 0.0f; }
// bf16 truncation pack: rel err <= 2^-8 = 0.4% << 0.101 threshold (proven r3-r8)
static __device__ __forceinline__ unsigned pk2(float a, float b) {
    return (__float_as_uint(a) >> 16) | (__float_as_uint(b) & 0xffff0000u);
}
static __device__ __forceinline__ float up_lo(unsigned u) { return __uint_as_float(u << 16); }
static __device__ __forceinline__ float up_hi(unsigned u) { return __uint_as_float(u & 0xffff0000u); }

// ---------------------------------------------------------------------------
// Two plain kernels, NO cross-block rendezvous. r2-r8 post-mortem: every
// spin/grid.sync variant cost 70-150us (device-scope polls thrash non-coherent
// per-XCD L2s) and register-resident fused variants spilled (compiler caps at
// 84 VGPR regardless of launch_bounds). The kernel boundary IS the cheap sync.
// vs the 155us r0 baseline: intermediates are bf16 in ws (25MB, not 48MB f32
// through out) and ch0 copy moved into splat -> finalize is a short stream.
// ---------------------------------------------------------------------------

// ---- Kernel A: splat. One block per (strip, z=b*3+m). h-pass from global
// (float4 + halo, L1 hits) -> LDS f32 tmp -> v-pass acc[4]/wave -> bf16 strip
// to ws + strip max. m==0 blocks also copy their ch0 strip. (r0 structure.)
__global__ __launch_bounds__(256) void splat_bf16(const float* __restrict__ x,
                                                  float* __restrict__ out,
                                                  unsigned* __restrict__ wsmaps,
                                                  float* __restrict__ maxws) {
    __shared__ float tmp[TROWS * TSTR];   // 24*260*4 = 24960 B -> 6 blocks/CU
    __shared__ float wred[4];

    const int strip = blockIdx.x;        // 0..15
    const int z = blockIdx.y;            // 0..191 = b*3+m
    const int b = z / 3;
    const int m = z - 3 * b;
    const int src_c = (m == 0) ? 2 : ((m == 1) ? 1 : 3);
    const float inv2s2 = (m == 2) ? 2.0f : 0.5f;   // 1/(2 sigma^2)

    float w[RR + 1];
#pragma unroll
    for (int d = 0; d <= RR; ++d) w[d] = __expf(-(float)(d * d) * inv2s2);

    const int ti0 = strip * OROWS;
    const float* xc = x + (((size_t)b * 4 + src_c) << 16);
    const int tid = threadIdx.x;

    // ---- ch0 strip copy (m==0 blocks only; 1024 f4 per strip / 256 thr) ----
    if (m == 0) {
        const float4* x0 = (const float4*)(x + (((size_t)b * 4) << 16));
        float4* o0 = (float4*)(out + (((size_t)b * 5) << 16));
        const int base = ti0 << 6;       // float4 index of strip start
#pragma unroll
        for (int i = 0; i < 4; ++i) {
            int q = base + i * 256 + tid;
            o0[q] = x0[q];
        }
    }

    // ---- h-stage: 24 rows x 32 groups (8 outputs each) = 768 tasks ----
#pragma unroll
    for (int t = 0; t < 3; ++t) {
        int idx = tid + t * 256;
        int r = idx >> 5;                // tmp row 0..23
        int g = idx & 31;                // cols 8g..8g+7
        int gi = ti0 + r - RR;           // image row
        float4 q0 = make_float4(0.f,0.f,0.f,0.f), q1 = q0, q2 = q0, q3 = q0;
        if (gi >= 0 && gi < HH) {
            const float4* row = (const float4*)(xc + ((size_t)gi << 8));
            int i0 = (g > 0) ? (2 * g - 1) : 0;
            int i3 = (g < 31) ? (2 * g + 2) : 63;
            q0 = row[i0];                // cols 8g-4..8g-1 (halo, L1 hit)
            q1 = row[2 * g];             // cols 8g..8g+3
            q2 = row[2 * g + 1];         // cols 8g+4..8g+7
            q3 = row[i3];                // cols 8g+8..8g+11 (halo, L1 hit)
            if (g == 0)  q0 = make_float4(0.f,0.f,0.f,0.f);
            if (g == 31) q3 = make_float4(0.f,0.f,0.f,0.f);
        }
        float a[16] = {bin(q0.x), bin(q0.y), bin(q0.z), bin(q0.w),
                       bin(q1.x), bin(q1.y), bin(q1.z), bin(q1.w),
                       bin(q2.x), bin(q2.y), bin(q2.z), bin(q2.w),
                       bin(q3.x), bin(q3.y), bin(q3.z), bin(q3.w)};
        float o[8];
#pragma unroll
        for (int j = 0; j < 8; ++j) {
            o[j] = w[4] * (a[j]     + a[j + 8])
                 + w[3] * (a[j + 1] + a[j + 7])
                 + w[2] * (a[j + 2] + a[j + 6])
                 + w[1] * (a[j + 3] + a[j + 5])
                 + w[0] *  a[j + 4];
        }
        float* trow = &tmp[r * TSTR + 8 * g];
        *(float4*)trow       = make_float4(o[0], o[1], o[2], o[3]);
        *(float4*)(trow + 4) = make_float4(o[4], o[5], o[6], o[7]);
    }
    __syncthreads();

    // ---- v-stage: wave gr -> out rows 4gr..4gr+3, lane c -> cols 4c..4c+3 ----
    const int c = tid & 63;
    const int gr = tid >> 6;             // 0..3 (one row-group per wave)
    float4 acc[4];
#pragma unroll
    for (int rr = 0; rr < 4; ++rr) acc[rr] = make_float4(0.f,0.f,0.f,0.f);
#pragma unroll
    for (int k = 0; k < 12; ++k) {       // all 64 lanes same row, contiguous b128
        float4 v = *(const float4*)&tmp[(4 * gr + k) * TSTR + 4 * c];
#pragma unroll
        for (int rr = 0; rr < 4; ++rr) {
            int d = k - RR - rr;
            if (d >= -RR && d <= RR) {
                float wk = w[d < 0 ? -d : d];
                acc[rr].x += wk * v.x; acc[rr].y += wk * v.y;
                acc[rr].z += wk * v.z; acc[rr].w += wk * v.w;
            }
        }
    }

    // ---- write unnormalized bf16 strip to ws (8B/lane contiguous) ----
    unsigned* wz = wsmaps + ((size_t)z << 15);   // 32768 u32 per z
    float lmax = 0.0f;
#pragma unroll
    for (int rr = 0; rr < 4; ++rr) {
        int row = ti0 + 4 * gr + rr;
        *(uint2*)&wz[row * 128 + 2 * c] = make_uint2(pk2(acc[rr].x, acc[rr].y),
                                                     pk2(acc[rr].z, acc[rr].w));
        lmax = fmaxf(lmax, fmaxf(fmaxf(acc[rr].x, acc[rr].y), fmaxf(acc[rr].z, acc[rr].w)));
    }

#pragma unroll
    for (int off = 32; off > 0; off >>= 1)
        lmax = fmaxf(lmax, __shfl_down(lmax, off, 64));
    if ((tid & 63) == 0) wred[tid >> 6] = lmax;
    __syncthreads();
    if (tid == 0)
        maxws[z * 16 + strip] = fmaxf(fmaxf(wred[0], wred[1]), fmaxf(wred[2], wred[3]));
}

// ---- Kernel B: finalize. One block per (b, 1/8 slab). Reduce 48 strip maxes,
// read bf16 maps (L3-hot), write normalized ch1..3 + ch4 = t*c. No ch0 work.
__global__ __launch_bounds__(256) void finalize_bf16(const unsigned* __restrict__ wsmaps,
                                                     const float* __restrict__ maxws,
                                                     float* __restrict__ out) {
    __shared__ float lds[48];
    const int b = blockIdx.x >> 3;
    const int slab = blockIdx.x & 7;
    const int tid = threadIdx.x;

    if (tid < 48) lds[tid] = maxws[b * 48 + tid];   // [m*16 + strip]
    __syncthreads();

    float mt = 0.f, mc = 0.f, mh = 0.f;
#pragma unroll
    for (int s = 0; s < 16; ++s) {                  // broadcast reads
        mt = fmaxf(mt, lds[s]);
        mc = fmaxf(mc, lds[16 + s]);
        mh = fmaxf(mh, lds[32 + s]);
    }
    if (mt == 0.f) mt = 1.f;
    if (mc == 0.f) mc = 1.f;
    if (mh == 0.f) mh = 1.f;
    const float rt = 1.f / mt, rc = 1.f / mc, rh = 1.f / mh;

    const int plane4 = HH * WW / 4;                 // 16384
    const unsigned* zt = wsmaps + ((size_t)(b * 3 + 0) << 15);
    const unsigned* zc = wsmaps + ((size_t)(b * 3 + 1) << 15);
    const unsigned* zh = wsmaps + ((size_t)(b * 3 + 2) << 15);
    float4* o = (float4*)(out + (((size_t)b * 5) << 16));

#pragma unroll
    for (int i = 0; i < 8; ++i) {
        int q = slab * 2048 + i * 256 + tid;        // plane float4 index
        uint2 tu = *(const uint2*)&zt[2 * q];       // u32 idx = 2q (8B coalesced)
        uint2 cu = *(const uint2*)&zc[2 * q];
        uint2 hu = *(const uint2*)&zh[2 * q];
        float4 t = make_float4(up_lo(tu.x) * rt, up_hi(tu.x) * rt,
                               up_lo(tu.y) * rt, up_hi(tu.y) * rt);
        float4 cc = make_float4(up_lo(cu.x) * rc, up_hi(cu.x) * rc,
                                up_lo(cu.y) * rc, up_hi(cu.y) * rc);
        float4 h = make_float4(up_lo(hu.x) * rh, up_hi(hu.x) * rh,
                               up_lo(hu.y) * rh, up_hi(hu.y) * rh);
        float4 mul = make_float4(t.x * cc.x, t.y * cc.y, t.z * cc.z, t.w * cc.w);
        o[plane4 + q] = t;
        o[2 * plane4 + q] = cc;
        o[3 * plane4 + q] = h;
        o[4 * plane4 + q] = mul;
    }
}

// ---------------------------------------------------------------------------
// Fallback pair (ws too small): verbatim r0 baseline (155us proven).
// ---------------------------------------------------------------------------
__global__ __launch_bounds__(256) void splat_f32(const float* __restrict__ x,
                                                 float* __restrict__ out,
                                                 float* __restrict__ maxws) {
    __shared__ float tmp[TROWS * TSTR];
    __shared__ float wred[4];
    const int strip = blockIdx.x;
    const int z = blockIdx.y;
    const int b = z / 3;
    const int m = z - 3 * b;
    const int src_c = (m == 0) ? 2 : ((m == 1) ? 1 : 3);
    const float inv2s2 = (m == 2) ? 2.0f : 0.5f;
    float w[RR + 1];
#pragma unroll
    for (int d = 0; d <= RR; ++d) w[d] = __expf(-(float)(d * d) * inv2s2);
    const int ti0 = strip * OROWS;
    const float* xc = x + (((size_t)b * 4 + src_c) << 16);
    const int tid = threadIdx.x;
#pragma unroll
    for (int t = 0; t < 3; ++t) {
        int idx = tid + t * 256;
        int r = idx >> 5;
        int g = idx & 31;
        int gi = ti0 + r - RR;
        float4 q0 = make_float4(0.f,0.f,0.f,0.f), q1 = q0, q2 = q0, q3 = q0;
        if (gi >= 0 && gi < HH) {
            const float4* row = (const float4*)(xc + ((size_t)gi << 8));
            int i0 = (g > 0) ? (2 * g - 1) : 0;
            int i3 = (g < 31) ? (2 * g + 2) : 63;
            q0 = row[i0]; q1 = row[2 * g]; q2 = row[2 * g + 1]; q3 = row[i3];
            if (g == 0)  q0 = make_float4(0.f,0.f,0.f,0.f);
            if (g == 31) q3 = make_float4(0.f,0.f,0.f,0.f);
        }
        float a[16] = {bin(q0.x), bin(q0.y), bin(q0.z), bin(q0.w),
                       bin(q1.x), bin(q1.y), bin(q1.z), bin(q1.w),
                       bin(q2.x), bin(q2.y), bin(q2.z), bin(q2.w),
                       bin(q3.x), bin(q3.y), bin(q3.z), bin(q3.w)};
        float o[8];
#pragma unroll
        for (int j = 0; j < 8; ++j) {
            o[j] = w[4] * (a[j] + a[j + 8]) + w[3] * (a[j + 1] + a[j + 7])
                 + w[2] * (a[j + 2] + a[j + 6]) + w[1] * (a[j + 3] + a[j + 5])
                 + w[0] * a[j + 4];
        }
        float* trow = &tmp[r * TSTR + 8 * g];
        *(float4*)trow       = make_float4(o[0], o[1], o[2], o[3]);
        *(float4*)(trow + 4) = make_float4(o[4], o[5], o[6], o[7]);
    }
    __syncthreads();
    const int c = tid & 63;
    const int gr = tid >> 6;
    float4 acc[4];
#pragma unroll
    for (int rr = 0; rr < 4; ++rr) acc[rr] = make_float4(0.f,0.f,0.f,0.f);
#pragma unroll
    for (int k = 0; k < 12; ++k) {
        float4 v = *(const float4*)&tmp[(4 * gr + k) * TSTR + 4 * c];
#pragma unroll
        for (int rr = 0; rr < 4; ++rr) {
            int d = k - RR - rr;
            if (d >= -RR && d <= RR) {
                float wk = w[d < 0 ? -d : d];
                acc[rr].x += wk * v.x; acc[rr].y += wk * v.y;
                acc[rr].z += wk * v.z; acc[rr].w += wk * v.w;
            }
        }
    }
    float* oc = out + (((size_t)b * 5 + (m + 1)) << 16);
    float lmax = 0.0f;
#pragma unroll
    for (int rr = 0; rr < 4; ++rr) {
        int row = ti0 + 4 * gr + rr;
        *(float4*)&oc[((size_t)row << 8) + 4 * c] = acc[rr];
        lmax = fmaxf(lmax, fmaxf(fmaxf(acc[rr].x, acc[rr].y), fmaxf(acc[rr].z, acc[rr].w)));
    }
#pragma unroll
    for (int off = 32; off > 0; off >>= 1)
        lmax = fmaxf(lmax, __shfl_down(lmax, off, 64));
    if ((tid & 63) == 0) wred[tid >> 6] = lmax;
    __syncthreads();
    if (tid == 0)
        maxws[z * 16 + strip] = fmaxf(fmaxf(wred[0], wred[1]), fmaxf(wred[2], wred[3]));
}

__global__ __launch_bounds__(256) void finalize_f32(const float* __restrict__ x,
                                                    float* __restrict__ out,
                                                    const float* __restrict__ maxws) {
    __shared__ float lds[48];
    const int b = blockIdx.x >> 3;
    const int slab = blockIdx.x & 7;
    const int tid = threadIdx.x;
    if (tid < 48) lds[tid] = maxws[b * 48 + tid];
    __syncthreads();
    float mt = 0.f, mc = 0.f, mh = 0.f;
#pragma unroll
    for (int s = 0; s < 16; ++s) {
        mt = fmaxf(mt, lds[s]);
        mc = fmaxf(mc, lds[16 + s]);
        mh = fmaxf(mh, lds[32 + s]);
    }
    if (mt == 0.f) mt = 1.f;
    if (mc == 0.f) mc = 1.f;
    if (mh == 0.f) mh = 1.f;
    const float rt = 1.f / mt, rc = 1.f / mc, rh = 1.f / mh;
    const int plane4 = HH * WW / 4;
    const float4* x0 = (const float4*)(x + ((size_t)b * 4 << 16));
    float4* o = (float4*)(out + ((size_t)b * 5 << 16));
#pragma unroll
    for (int i = 0; i < 8; ++i) {
        int q = slab * 2048 + i * 256 + tid;
        float4 c0 = x0[q];
        float4 t = o[plane4 + q];
        float4 c = o[2 * plane4 + q];
        float4 h = o[3 * plane4 + q];
        t.x *= rt; t.y *= rt; t.z *= rt; t.w *= rt;
        c.x *= rc; c.y *= rc; c.z *= rc; c.w *= rc;
        h.x *= rh; h.y *= rh; h.z *= rh; h.w *= rh;
        float4 mul = make_float4(t.x * c.x, t.y * c.y, t.z * c.z, t.w * c.w);
        o[q] = c0;
        o[plane4 + q] = t;
        o[2 * plane4 + q] = c;
        o[3 * plane4 + q] = h;
        o[4 * plane4 + q] = mul;
    }
}

extern "C" void kernel_launch(void* const* d_in, const int* in_sizes, int n_in,
                              void* d_out, int out_size, void* d_ws, size_t ws_size,
                              hipStream_t stream) {
    const float* x = (const float*)d_in[0];
    float* out = (float*)d_out;

    if (ws_size >= NEED_WS) {
        unsigned* wsmaps = (unsigned*)d_ws;
        float* maxws = (float*)d_ws + MAPS_U32;
        hipLaunchKernelGGL(splat_bf16, dim3(16, 192), dim3(256), 0, stream,
                           x, out, wsmaps, maxws);
        hipLaunchKernelGGL(finalize_bf16, dim3(BB * 8), dim3(256), 0, stream,
                           wsmaps, maxws, out);
    } else {
        float* maxws = (float*)d_ws;   // 12 KB strip maxes
        hipLaunchKernelGGL(splat_f32, dim3(16, 192), dim3(256), 0, stream,
                           x, out, maxws);
        hipLaunchKernelGGL(finalize_f32, dim3(BB * 8), dim3(256), 0, stream,
                           x, out, maxws);
    }
}

// Round 11
// 140.189 us; speedup vs baseline: 1.8997x; 1.0158x over previous
//
#include <hip/hip_runtime.h>
#include <cmath>

#define HH 256
#define WW 256
#define BB 64
#define RR 4               // tap radius: exp(-12.5)=3.7e-6 dropped -> error ~4e-5 << 0.1 thresh
#define OROWS 16           // output rows per block
#define TROWS (OROWS + 2*RR)  // 24 h-blurred rows in LDS
#define TSTR 260           // tmp row stride (dwords): 256 + 4 -> rows rotate 4 banks

#define MAPS_U32 ((size_t)192 * 16384)            // u8 maps: 192 z-planes x 64KB

static __device__ __forceinline__ float bin(float v) { return (v > 0.0f) ? 1.0f : 0.0f; }

// ---------------------------------------------------------------------------
// Two plain kernels (r9 structure — kernel boundary is the sync; all
// rendezvous variants r2-r8 lost 70-150us to cross-XCD coherence traffic).
// r10 change: intermediate maps stored as u8 with PER-STRIP scale (the strip
// max is already computed for the normalization reduce). Decode error after
// global normalize <= 0.5/255*strip_max/M <= 0.002 (ch4 ~0.004) << 0.101
// threshold. Intermediate traffic 50 MB -> 25 MB round trip.
// map 0: x[:,2] s=1.0 -> ch1 ; map 1: x[:,1] -> ch2 ; map 2: x[:,3] s=0.5 -> ch3
// (r11 = r10 resubmitted byte-identical: round-10 failure was the broker,
//  not the kernel — no spin/coop/atomics, statically bounded execution.)
// ---------------------------------------------------------------------------

// ---- Kernel A: splat. One block per (strip, z=b*3+m). h-pass from global
// (float4 + halo, L1/L3 hits) -> LDS f32 tmp -> v-pass acc[4]/wave -> strip
// max -> u8-packed strip to ws. m==0 blocks also copy their ch0 strip.
__global__ __launch_bounds__(256) void splat_u8(const float* __restrict__ x,
                                                float* __restrict__ out,
                                                unsigned* __restrict__ wsmaps,
                                                float* __restrict__ maxws) {
    __shared__ float tmp[TROWS * TSTR];   // 24*260*4 = 24960 B -> 6 blocks/CU
    __shared__ float wred[4];

    const int strip = blockIdx.x;        // 0..15
    const int z = blockIdx.y;            // 0..191 = b*3+m
    const int b = z / 3;
    const int m = z - 3 * b;
    const int src_c = (m == 0) ? 2 : ((m == 1) ? 1 : 3);
    const float inv2s2 = (m == 2) ? 2.0f : 0.5f;   // 1/(2 sigma^2)

    float w[RR + 1];
#pragma unroll
    for (int d = 0; d <= RR; ++d) w[d] = __expf(-(float)(d * d) * inv2s2);

    const int ti0 = strip * OROWS;
    const float* xc = x + (((size_t)b * 4 + src_c) << 16);
    const int tid = threadIdx.x;

    // ---- ch0 strip copy (m==0 blocks only) ----
    if (m == 0) {
        const float4* x0 = (const float4*)(x + (((size_t)b * 4) << 16));
        float4* o0 = (float4*)(out + (((size_t)b * 5) << 16));
        const int base = ti0 << 6;       // float4 index of strip start
#pragma unroll
        for (int i = 0; i < 4; ++i) {
            int q = base + i * 256 + tid;
            o0[q] = x0[q];
        }
    }

    // ---- h-stage: 24 rows x 32 groups (8 outputs each) = 768 tasks ----
#pragma unroll
    for (int t = 0; t < 3; ++t) {
        int idx = tid + t * 256;
        int r = idx >> 5;                // tmp row 0..23
        int g = idx & 31;                // cols 8g..8g+7
        int gi = ti0 + r - RR;           // image row
        float4 q0 = make_float4(0.f,0.f,0.f,0.f), q1 = q0, q2 = q0, q3 = q0;
        if (gi >= 0 && gi < HH) {
            const float4* row = (const float4*)(xc + ((size_t)gi << 8));
            int i0 = (g > 0) ? (2 * g - 1) : 0;
            int i3 = (g < 31) ? (2 * g + 2) : 63;
            q0 = row[i0];                // cols 8g-4..8g-1 (halo, L1 hit)
            q1 = row[2 * g];             // cols 8g..8g+3
            q2 = row[2 * g + 1];         // cols 8g+4..8g+7
            q3 = row[i3];                // cols 8g+8..8g+11 (halo, L1 hit)
            if (g == 0)  q0 = make_float4(0.f,0.f,0.f,0.f);
            if (g == 31) q3 = make_float4(0.f,0.f,0.f,0.f);
        }
        float a[16] = {bin(q0.x), bin(q0.y), bin(q0.z), bin(q0.w),
                       bin(q1.x), bin(q1.y), bin(q1.z), bin(q1.w),
                       bin(q2.x), bin(q2.y), bin(q2.z), bin(q2.w),
                       bin(q3.x), bin(q3.y), bin(q3.z), bin(q3.w)};
        float o[8];
#pragma unroll
        for (int j = 0; j < 8; ++j) {
            o[j] = w[4] * (a[j]     + a[j + 8])
                 + w[3] * (a[j + 1] + a[j + 7])
                 + w[2] * (a[j + 2] + a[j + 6])
                 + w[1] * (a[j + 3] + a[j + 5])
                 + w[0] *  a[j + 4];
        }
        float* trow = &tmp[r * TSTR + 8 * g];
        *(float4*)trow       = make_float4(o[0], o[1], o[2], o[3]);
        *(float4*)(trow + 4) = make_float4(o[4], o[5], o[6], o[7]);
    }
    __syncthreads();

    // ---- v-stage: wave gr -> out rows 4gr..4gr+3, lane c -> cols 4c..4c+3 ----
    const int c = tid & 63;
    const int gr = tid >> 6;             // 0..3 (one row-group per wave)
    float4 acc[4];
#pragma unroll
    for (int rr = 0; rr < 4; ++rr) acc[rr] = make_float4(0.f,0.f,0.f,0.f);
#pragma unroll
    for (int k = 0; k < 12; ++k) {       // all 64 lanes same row, contiguous b128
        float4 v = *(const float4*)&tmp[(4 * gr + k) * TSTR + 4 * c];
#pragma unroll
        for (int rr = 0; rr < 4; ++rr) {
            int d = k - RR - rr;
            if (d >= -RR && d <= RR) {
                float wk = w[d < 0 ? -d : d];
                acc[rr].x += wk * v.x; acc[rr].y += wk * v.y;
                acc[rr].z += wk * v.z; acc[rr].w += wk * v.w;
            }
        }
    }

    // ---- strip max FIRST (needed as the u8 quantization scale) ----
    float lmax = 0.0f;
#pragma unroll
    for (int rr = 0; rr < 4; ++rr)
        lmax = fmaxf(lmax, fmaxf(fmaxf(acc[rr].x, acc[rr].y), fmaxf(acc[rr].z, acc[rr].w)));
#pragma unroll
    for (int off = 32; off > 0; off >>= 1)
        lmax = fmaxf(lmax, __shfl_down(lmax, off, 64));
    if (c == 0) wred[gr] = lmax;
    __syncthreads();
    const float smax = fmaxf(fmaxf(wred[0], wred[1]), fmaxf(wred[2], wred[3]));
    if (tid == 0) maxws[z * 16 + strip] = smax;
    const float scale = (smax > 0.0f) ? (255.0f / smax) : 0.0f;

    // ---- pack u8 strip to ws: one u32 per lane per row (256B/wave) ----
    unsigned* wz = wsmaps + ((size_t)z << 14);   // 16384 u32 per z-plane
#pragma unroll
    for (int rr = 0; rr < 4; ++rr) {
        int row = ti0 + 4 * gr + rr;
        unsigned u0 = __float2uint_rn(acc[rr].x * scale); u0 = u0 > 255u ? 255u : u0;
        unsigned u1 = __float2uint_rn(acc[rr].y * scale); u1 = u1 > 255u ? 255u : u1;
        unsigned u2 = __float2uint_rn(acc[rr].z * scale); u2 = u2 > 255u ? 255u : u2;
        unsigned u3 = __float2uint_rn(acc[rr].w * scale); u3 = u3 > 255u ? 255u : u3;
        wz[row * 64 + c] = u0 | (u1 << 8) | (u2 << 16) | (u3 << 24);
    }
}

// ---- Kernel B: finalize. One block per (b, 1/8 slab). Reduce 48 strip maxes,
// pre-scale 48 decode factors (strip_max * r_map / 255), read u8 maps
// (L3-hot), write normalized ch1..3 + ch4 = t*c.
__global__ __launch_bounds__(256) void finalize_u8(const unsigned* __restrict__ wsmaps,
                                                   const float* __restrict__ maxws,
                                                   float* __restrict__ out) {
    __shared__ float lds[48];
    const int b = blockIdx.x >> 3;
    const int slab = blockIdx.x & 7;
    const int tid = threadIdx.x;

    if (tid < 48) lds[tid] = maxws[b * 48 + tid];   // [m*16 + strip]
    __syncthreads();

    float mt = 0.f, mc = 0.f, mh = 0.f;
#pragma unroll
    for (int s = 0; s < 16; ++s) {                  // broadcast reads
        mt = fmaxf(mt, lds[s]);
        mc = fmaxf(mc, lds[16 + s]);
        mh = fmaxf(mh, lds[32 + s]);
    }
    if (mt == 0.f) mt = 1.f;
    if (mc == 0.f) mc = 1.f;
    if (mh == 0.f) mh = 1.f;
    const float rt = 1.f / mt, rc = 1.f / mc, rh = 1.f / mh;
    __syncthreads();                                // all reads done before rewrite
    if (tid < 48) {
        const float rm = (tid < 16) ? rt : ((tid < 32) ? rc : rh);
        lds[tid] = lds[tid] * rm * (1.0f / 255.0f); // decode factor per (m,strip)
    }
    __syncthreads();

    const int plane4 = HH * WW / 4;                 // 16384
    const unsigned* zt = wsmaps + ((size_t)(b * 3 + 0) << 14);
    const unsigned* zc = wsmaps + ((size_t)(b * 3 + 1) << 14);
    const unsigned* zh = wsmaps + ((size_t)(b * 3 + 2) << 14);
    float4* o = (float4*)(out + (((size_t)b * 5) << 16));

#pragma unroll
    for (int i = 0; i < 8; ++i) {
        int q = slab * 2048 + i * 256 + tid;        // plane float4 index
        int st = q >> 10;                           // strip (uniform per i)
        float dt = lds[st], dc = lds[16 + st], dh = lds[32 + st];
        unsigned tu = zt[q], cu = zc[q], hu = zh[q];
        float4 t = make_float4((float)(tu & 255u) * dt, (float)((tu >> 8) & 255u) * dt,
                               (float)((tu >> 16) & 255u) * dt, (float)(tu >> 24) * dt);
        float4 cc = make_float4((float)(cu & 255u) * dc, (float)((cu >> 8) & 255u) * dc,
                                (float)((cu >> 16) & 255u) * dc, (float)(cu >> 24) * dc);
        float4 h = make_float4((float)(hu & 255u) * dh, (float)((hu >> 8) & 255u) * dh,
                               (float)((hu >> 16) & 255u) * dh, (float)(hu >> 24) * dh);
        float4 mul = make_float4(t.x * cc.x, t.y * cc.y, t.z * cc.z, t.w * cc.w);
        o[plane4 + q] = t;
        o[2 * plane4 + q] = cc;
        o[3 * plane4 + q] = h;
        o[4 * plane4 + q] = mul;
    }
}

extern "C" void kernel_launch(void* const* d_in, const int* in_sizes, int n_in,
                              void* d_out, int out_size, void* d_ws, size_t ws_size,
                              hipStream_t stream) {
    const float* x = (const float*)d_in[0];
    float* out = (float*)d_out;
    unsigned* wsmaps = (unsigned*)d_ws;                 // 12.58 MB u8 maps
    float* maxws = (float*)d_ws + MAPS_U32;             // + 12 KB strip maxes

    hipLaunchKernelGGL(splat_u8, dim3(16, 192), dim3(256), 0, stream,
                       x, out, wsmaps, maxws);
    hipLaunchKernelGGL(finalize_u8, dim3(BB * 8), dim3(256), 0, stream,
                       wsmaps, maxws, out);
}